// Round 7
// baseline (493.795 us; speedup 1.0000x reference)
//
#include <hip/hip_runtime.h>

#define F_IN 256
#define F_OUT 64
#define BSH 7             // bin width 128 nodes
#define BINW 128
#define NBINS_CAP 512     // LDS histogram capacity (N <= 65536)
#define BATCH 2048        // edges per block in bin_count (8 per thread)

typedef __attribute__((ext_vector_type(8))) short short8;
typedef __attribute__((ext_vector_type(4))) float f32x4;

// ---------------------------------------------------------------------------
// bf16 helpers. hi = truncated bf16, lo = RNE bf16 of exact residual.
// ---------------------------------------------------------------------------
__device__ inline unsigned short f2bf_rne(float f) {
    unsigned u = __float_as_uint(f);
    return (unsigned short)((u + 0x7fffu + ((u >> 16) & 1u)) >> 16);
}
__device__ inline float trunc_res(float f) {
    return f - __uint_as_float(__float_as_uint(f) & 0xFFFF0000u);
}
__device__ inline float bf_lo(unsigned u) { return __uint_as_float(u << 16); }
__device__ inline float bf_hi(unsigned u) { return __uint_as_float(u & 0xFFFF0000u); }
__device__ inline short8 pack_hi(float4 a, float4 b) {
    union { unsigned u[4]; short8 s; } r;
    r.u[0] = (__float_as_uint(a.x) >> 16) | (__float_as_uint(a.y) & 0xFFFF0000u);
    r.u[1] = (__float_as_uint(a.z) >> 16) | (__float_as_uint(a.w) & 0xFFFF0000u);
    r.u[2] = (__float_as_uint(b.x) >> 16) | (__float_as_uint(b.y) & 0xFFFF0000u);
    r.u[3] = (__float_as_uint(b.z) >> 16) | (__float_as_uint(b.w) & 0xFFFF0000u);
    return r.s;
}
__device__ inline short8 pack_lo(float4 a, float4 b) {
    union { unsigned u[4]; short8 s; } r;
    r.u[0] = f2bf_rne(trunc_res(a.x)) | ((unsigned)f2bf_rne(trunc_res(a.y)) << 16);
    r.u[1] = f2bf_rne(trunc_res(a.z)) | ((unsigned)f2bf_rne(trunc_res(a.w)) << 16);
    r.u[2] = f2bf_rne(trunc_res(b.x)) | ((unsigned)f2bf_rne(trunc_res(b.y)) << 16);
    r.u[3] = f2bf_rne(trunc_res(b.z)) | ((unsigned)f2bf_rne(trunc_res(b.w)) << 16);
    return r.s;
}

// ---------------------------------------------------------------------------
// K1: bin edges by dst>>BSH into per-bin staging (packed u32: src | dstLow<<16;
// requires N <= 65536) + global deg histogram. Tiny LDS (4 KB) -> high
// occupancy; 8 independent edges/thread. Block slots are dense per bin window
// so L2 merges the scattered stores (R5/R6 evidence: WRITE_SIZE ~ footprint).
// ---------------------------------------------------------------------------
__global__ __launch_bounds__(256) void bin_count(const int* __restrict__ adj,
                                                 unsigned* __restrict__ staging,
                                                 int* __restrict__ cursor,
                                                 int* __restrict__ deg,
                                                 int E, int nbins, int maxBin) {
    __shared__ int cnt[NBINS_CAP];
    __shared__ int base[NBINS_CAP];
    const int tid = threadIdx.x;
    for (int i = tid; i < NBINS_CAP; i += 256) cnt[i] = 0;
    __syncthreads();

    const int e0 = blockIdx.x * BATCH;
    const int e1 = min(e0 + BATCH, E);
    const int e = e0 + tid * 8;
    union { int4 v[2]; int a[8]; } S, D;
    int sl[8];
    int nv = 0;
    if (e < e1) {
        if (e + 8 <= e1 && ((E & 3) == 0)) {
            S.v[0] = *(const int4*)&adj[e];
            S.v[1] = *(const int4*)&adj[e + 4];
            D.v[0] = *(const int4*)&adj[E + e];
            D.v[1] = *(const int4*)&adj[E + e + 4];
            nv = 8;
        } else {
            for (int k = 0; k < 8 && e + k < e1; k++) {
                S.a[k] = adj[e + k];
                D.a[k] = adj[E + e + k];
                nv++;
            }
        }
    }
#pragma unroll
    for (int j = 0; j < 8; j++) {
        if (j < nv) {
            sl[j] = atomicAdd(&cnt[D.a[j] >> BSH], 1);
            atomicAdd(&deg[D.a[j]], 1);
        }
    }
    __syncthreads();
    for (int i = tid; i < nbins; i += 256) base[i] = atomicAdd(&cursor[i], cnt[i]);
    __syncthreads();
#pragma unroll
    for (int j = 0; j < 8; j++) {
        if (j < nv) {
            int b = D.a[j] >> BSH;
            int pos = base[b] + sl[j];
            if (pos < maxBin)
                staging[(size_t)b * maxBin + pos] =
                    (unsigned)S.a[j] | ((unsigned)(D.a[j] & (BINW - 1)) << 16);
        }
    }
}

// ---------------------------------------------------------------------------
// K2: g(bf16) = rsqrt(deg+1) * (x @ W) via bf16 MFMA, x = hi+lo split
// (near-fp32). 512-thread blocks, 16 nodes/wave, W staged per block into
// B-fragment-major LDS (u32-packed bf16 pairs, 32 KB).
// ---------------------------------------------------------------------------
__global__ __launch_bounds__(512, 4) void gemm_mfma(const float* __restrict__ x,
                                                    const float* __restrict__ W,
                                                    const int* __restrict__ deg,
                                                    unsigned* __restrict__ gu, int N) {
    __shared__ unsigned Wf[32 * 64 * 4];  // 32 KB: [kchunk][n][4 x u32(bf16x2)]
    for (int p = threadIdx.x; p < (F_IN / 2) * F_OUT; p += 512) {
        int kp = p >> 6;
        int n = p & 63;
        int k = kp * 2;
        unsigned lo = f2bf_rne(W[k * F_OUT + n]);
        unsigned hi = f2bf_rne(W[(k + 1) * F_OUT + n]);
        Wf[((k >> 3) * 64 + n) * 4 + ((k & 7) >> 1)] = lo | (hi << 16);
    }
    __syncthreads();

    const int wave = threadIdx.x >> 6;
    const int lane = threadIdx.x & 63;
    const int q = lane >> 4;
    const int c = lane & 15;
    const int n0 = blockIdx.x * 128 + wave * 16;
    const int r = min(n0 + c, N - 1);
    const float* p0 = x + (size_t)r * F_IN + q * 8;

    f32x4 acc[4] = {};
#pragma unroll
    for (int s = 0; s < 8; s++) {
        float4 a0 = *(const float4*)(p0 + s * 32);
        float4 a1 = *(const float4*)(p0 + s * 32 + 4);
        short8 ah = pack_hi(a0, a1), al = pack_lo(a0, a1);
#pragma unroll
        for (int t = 0; t < 4; t++) {
            short8 bh = *(const short8*)&Wf[((s * 4 + q) * 64 + t * 16 + c) * 4];
            acc[t] = __builtin_amdgcn_mfma_f32_16x16x32_bf16(ah, bh, acc[t], 0, 0, 0);
            acc[t] = __builtin_amdgcn_mfma_f32_16x16x32_bf16(al, bh, acc[t], 0, 0, 0);
        }
    }

    // D layout: col = t*16 + c (feature), row = q*4 + rr (node). Pack col
    // pairs via shfl_xor(1), store bf16x2.
#pragma unroll
    for (int rr = 0; rr < 4; rr++) {
        int node = n0 + q * 4 + rr;
        float dv = rsqrtf((float)deg[min(node, N - 1)] + 1.0f);
#pragma unroll
        for (int t = 0; t < 4; t++) {
            float v = acc[t][rr] * dv;
            float o = __shfl_xor(v, 1, 64);
            if (node < N && !(lane & 1)) {
                unsigned pk = (unsigned)f2bf_rne(v) | ((unsigned)f2bf_rne(o) << 16);
                gu[(size_t)node * 32 + t * 8 + (c >> 1)] = pk;
            }
        }
    }
}

// ---------------------------------------------------------------------------
// K3: per-bin aggregate + fused epilogue (replaces scan+scatter+gather+CSR).
// One block per 128-node bin; LDS fp32 acc[128][64] (32 KB). Each half-wave
// processes one edge: 32 lanes read the src's 128B bf16 g-row coalesced and
// LDS-atomicAdd 64 floats into acc[dstLow]. 2x unrolled for MLP. Epilogue:
// out = relu(dinv*(acc + g_self) + bias).
// ---------------------------------------------------------------------------
__global__ __launch_bounds__(512, 4) void aggregate(const unsigned* __restrict__ staging,
                                                    const int* __restrict__ cursor,
                                                    const int* __restrict__ deg,
                                                    const unsigned* __restrict__ gu,
                                                    const float* __restrict__ bias,
                                                    float* __restrict__ out,
                                                    int N, int maxBin) {
    __shared__ float acc[BINW * F_OUT];  // 32 KB
    const int tid = threadIdx.x;
    const int b = blockIdx.x;
    const int nb0 = b << BSH;
    for (int i = tid; i < BINW * F_OUT; i += 512) acc[i] = 0.0f;
    __syncthreads();

    const int segCnt = min(cursor[b], maxBin);
    const unsigned* seg = staging + (size_t)b * maxBin;
    const int wv = tid >> 6;
    const int half = (tid >> 5) & 1;
    const int li = tid & 31;

    int i = wv * 2 + half;  // 16 half-waves per block, stride 16
    for (; i + 16 < segCnt; i += 32) {
        unsigned e0 = seg[i], e1 = seg[i + 16];
        unsigned g0 = gu[(size_t)(e0 & 0xFFFFu) * 32 + li];
        unsigned g1 = gu[(size_t)(e1 & 0xFFFFu) * 32 + li];
        int d0 = (int)(e0 >> 16) * 64 + li * 2;
        int d1 = (int)(e1 >> 16) * 64 + li * 2;
        atomicAdd(&acc[d0], bf_lo(g0));
        atomicAdd(&acc[d0 + 1], bf_hi(g0));
        atomicAdd(&acc[d1], bf_lo(g1));
        atomicAdd(&acc[d1 + 1], bf_hi(g1));
    }
    for (; i < segCnt; i += 16) {
        unsigned e0 = seg[i];
        unsigned g0 = gu[(size_t)(e0 & 0xFFFFu) * 32 + li];
        int d0 = (int)(e0 >> 16) * 64 + li * 2;
        atomicAdd(&acc[d0], bf_lo(g0));
        atomicAdd(&acc[d0 + 1], bf_hi(g0));
    }
    __syncthreads();

    const int nn = min(BINW, N - nb0);
    for (int j = tid; j < nn * 32; j += 512) {
        int n = j >> 5, jj = j & 31;
        int node = nb0 + n;
        unsigned gs = gu[(size_t)node * 32 + jj];  // self loop
        float dv = rsqrtf((float)deg[node] + 1.0f);
        float2 bb = ((const float2*)bias)[jj];
        float a0 = acc[n * 64 + jj * 2] + bf_lo(gs);
        float a1 = acc[n * 64 + jj * 2 + 1] + bf_hi(gs);
        float2 r;
        r.x = fmaxf(fmaf(dv, a0, bb.x), 0.0f);
        r.y = fmaxf(fmaf(dv, a1, bb.y), 0.0f);
        ((float2*)out)[(size_t)node * 32 + jj] = r;
    }
}

extern "C" void kernel_launch(void* const* d_in, const int* in_sizes, int n_in,
                              void* d_out, int out_size, void* d_ws, size_t ws_size,
                              hipStream_t stream) {
    const float* x = (const float*)d_in[0];
    const int* adj = (const int*)d_in[1];
    const float* W = (const float*)d_in[2];
    const float* b = (const float*)d_in[3];
    float* out = (float*)d_out;

    const int N = in_sizes[0] / F_IN;  // 50000 (packing assumes N <= 65536)
    const int E = in_sizes[1] / 2;     // 800000
    const int nbins = (N + BINW - 1) >> BSH;             // 391 (<= NBINS_CAP)
    const int avg = (E + nbins - 1) / nbins;             // ~2046
    const int maxBin = ((avg + (avg >> 2)) + 63) & ~63;  // 2560, >11 sd headroom

    // ws: deg(N) | cursor(512) | staging(nbins*maxBin u32) | g(N*32 u32)
    char* ws = (char*)d_ws;
    size_t segDeg = (((size_t)N * 4) + 255) & ~(size_t)255;
    int* deg = (int*)ws;
    int* cursor = (int*)(ws + segDeg);
    unsigned* staging = (unsigned*)(ws + segDeg + 2048);
    size_t stagingBytes = (((size_t)nbins * maxBin * 4) + 255) & ~(size_t)255;
    unsigned* g16 = (unsigned*)(ws + segDeg + 2048 + stagingBytes);

    hipMemsetAsync(ws, 0, segDeg + 2048, stream);  // deg + cursor in one call

    bin_count<<<(E + BATCH - 1) / BATCH, 256, 0, stream>>>(adj, staging, cursor,
                                                           deg, E, nbins, maxBin);
    gemm_mfma<<<(N + 127) / 128, 512, 0, stream>>>(x, W, deg, g16, N);
    aggregate<<<nbins, 512, 0, stream>>>(staging, cursor, deg, g16, b, out, N, maxBin);
}

// Round 9
// 179.907 us; speedup vs baseline: 2.7447x; 2.7447x over previous
//
#include <hip/hip_runtime.h>

#define F_IN 256
#define F_OUT 64
#define BSH 7             // bin width 128 nodes
#define BINW 128
#define NBINS_CAP 512     // LDS histogram capacity in bin_count (N <= 65536)
#define BATCH 2048        // edges per block in bin_count (8 per thread)

typedef __attribute__((ext_vector_type(8))) short short8;
typedef __attribute__((ext_vector_type(4))) float f32x4;

// ---------------------------------------------------------------------------
// bf16 helpers. hi = truncated bf16, lo = RNE bf16 of exact residual.
// ---------------------------------------------------------------------------
__device__ inline unsigned short f2bf_rne(float f) {
    unsigned u = __float_as_uint(f);
    return (unsigned short)((u + 0x7fffu + ((u >> 16) & 1u)) >> 16);
}
__device__ inline float trunc_res(float f) {
    return f - __uint_as_float(__float_as_uint(f) & 0xFFFF0000u);
}
__device__ inline float bf_lo(unsigned u) { return __uint_as_float(u << 16); }
__device__ inline float bf_hi(unsigned u) { return __uint_as_float(u & 0xFFFF0000u); }
__device__ inline short8 pack_hi(float4 a, float4 b) {
    union { unsigned u[4]; short8 s; } r;
    r.u[0] = (__float_as_uint(a.x) >> 16) | (__float_as_uint(a.y) & 0xFFFF0000u);
    r.u[1] = (__float_as_uint(a.z) >> 16) | (__float_as_uint(a.w) & 0xFFFF0000u);
    r.u[2] = (__float_as_uint(b.x) >> 16) | (__float_as_uint(b.y) & 0xFFFF0000u);
    r.u[3] = (__float_as_uint(b.z) >> 16) | (__float_as_uint(b.w) & 0xFFFF0000u);
    return r.s;
}
__device__ inline short8 pack_lo(float4 a, float4 b) {
    union { unsigned u[4]; short8 s; } r;
    r.u[0] = f2bf_rne(trunc_res(a.x)) | ((unsigned)f2bf_rne(trunc_res(a.y)) << 16);
    r.u[1] = f2bf_rne(trunc_res(a.z)) | ((unsigned)f2bf_rne(trunc_res(a.w)) << 16);
    r.u[2] = f2bf_rne(trunc_res(b.x)) | ((unsigned)f2bf_rne(trunc_res(b.y)) << 16);
    r.u[3] = f2bf_rne(trunc_res(b.z)) | ((unsigned)f2bf_rne(trunc_res(b.w)) << 16);
    return r.s;
}

// ---------------------------------------------------------------------------
// K1: bin edges by dst>>BSH into per-bin staging (packed u32: src | dstLow<<16,
// valid for N <= 65536) + global deg histogram. Tiny LDS -> high occupancy,
// 8 independent edges/thread. Block slots are dense per bin window (L2 merges
// the stores -- R5/R6 WRITE_SIZE evidence).
// ---------------------------------------------------------------------------
__global__ __launch_bounds__(256) void bin_count(const int* __restrict__ adj,
                                                 unsigned* __restrict__ staging,
                                                 int* __restrict__ cursor,
                                                 int* __restrict__ deg,
                                                 int E, int nbins, int maxBin) {
    __shared__ int cnt[NBINS_CAP];
    __shared__ int base[NBINS_CAP];
    const int tid = threadIdx.x;
    for (int i = tid; i < NBINS_CAP; i += 256) cnt[i] = 0;
    __syncthreads();

    const int e0 = blockIdx.x * BATCH;
    const int e1 = min(e0 + BATCH, E);
    const int e = e0 + tid * 8;
    union { int4 v[2]; int a[8]; } S, D;
    int sl[8];
    int nv = 0;
    if (e < e1) {
        if (e + 8 <= e1 && ((E & 3) == 0)) {
            S.v[0] = *(const int4*)&adj[e];
            S.v[1] = *(const int4*)&adj[e + 4];
            D.v[0] = *(const int4*)&adj[E + e];
            D.v[1] = *(const int4*)&adj[E + e + 4];
            nv = 8;
        } else {
            for (int k = 0; k < 8 && e + k < e1; k++) {
                S.a[k] = adj[e + k];
                D.a[k] = adj[E + e + k];
                nv++;
            }
        }
    }
#pragma unroll
    for (int j = 0; j < 8; j++) {
        if (j < nv) {
            sl[j] = atomicAdd(&cnt[D.a[j] >> BSH], 1);
            atomicAdd(&deg[D.a[j]], 1);
        }
    }
    __syncthreads();
    for (int i = tid; i < nbins; i += 256) base[i] = atomicAdd(&cursor[i], cnt[i]);
    __syncthreads();
#pragma unroll
    for (int j = 0; j < 8; j++) {
        if (j < nv) {
            int b = D.a[j] >> BSH;
            int pos = base[b] + sl[j];
            if (pos < maxBin)
                staging[(size_t)b * maxBin + pos] =
                    (unsigned)S.a[j] | ((unsigned)(D.a[j] & (BINW - 1)) << 16);
        }
    }
}

// ---------------------------------------------------------------------------
// K2: fused scan+scatter, one block per 128-node bin (391-way parallel).
// Wave 0 reduces prior-bin counts for the global base; LDS histogram of
// staged dstLows; 2-wave exclusive scan; write rowOff; scatter srcs into
// csr (ushort) via LDS cursors. csr writes land in one ~4KB window per block.
// ---------------------------------------------------------------------------
__global__ __launch_bounds__(256) void build_csr(const unsigned* __restrict__ staging,
                                                 const int* __restrict__ cursor,
                                                 int* __restrict__ rowOff,
                                                 unsigned short* __restrict__ csr,
                                                 int N, int maxBin, int nbins) {
    __shared__ int degL[BINW];
    __shared__ int cur[BINW];
    __shared__ int wsum[2];
    __shared__ int baseSh;
    const int b = blockIdx.x;
    const int tid = threadIdx.x;
    const int nb0 = b << BSH;
    const int segCnt = min(cursor[b], maxBin);
    const unsigned* seg = staging + (size_t)b * maxBin;

    if (tid < 64) {  // base = staged edges in bins before this one
        int v = 0;
        for (int j = tid; j < b; j += 64) v += min(cursor[j], maxBin);
        for (int d = 1; d < 64; d <<= 1) v += __shfl_xor(v, d, 64);
        if (tid == 0) baseSh = v;
    }
    if (tid < BINW) degL[tid] = 0;
    __syncthreads();
    const int base = baseSh;

    for (int i = tid; i < segCnt; i += 256) atomicAdd(&degL[seg[i] >> 16], 1);
    __syncthreads();

    int incl = 0, v = 0;
    if (tid < BINW) {  // 2-wave exclusive scan of degL[128]
        const int lane = tid & 63;
        v = degL[tid];
        incl = v;
        for (int d = 1; d < 64; d <<= 1) {
            int t = __shfl_up(incl, d, 64);
            if (lane >= d) incl += t;
        }
        if (lane == 63) wsum[tid >> 6] = incl;
    }
    __syncthreads();
    if (tid < BINW) {
        int ex = incl - v + ((tid >= 64) ? wsum[0] : 0);
        cur[tid] = ex;
        int node = nb0 + tid;
        if (node < N) rowOff[node] = base + ex;
    }
    if (b == nbins - 1 && tid == 0) rowOff[N] = base + segCnt;
    __syncthreads();

    for (int i = tid; i < segCnt; i += 256) {
        unsigned e = seg[i];
        int pos = atomicAdd(&cur[e >> 16], 1);
        csr[base + pos] = (unsigned short)(e & 0xFFFFu);
    }
}

// ---------------------------------------------------------------------------
// K3: g(bf16) = rsqrt(deg+1) * (x @ W) via bf16 MFMA, x = hi+lo split
// (near-fp32). 512-thread blocks, 16 nodes/wave, W staged per block into
// B-fragment-major LDS (u32-packed bf16 pairs, 32 KB).
// ---------------------------------------------------------------------------
__global__ __launch_bounds__(512, 4) void gemm_mfma(const float* __restrict__ x,
                                                    const float* __restrict__ W,
                                                    const int* __restrict__ deg,
                                                    unsigned* __restrict__ gu, int N) {
    __shared__ unsigned Wf[32 * 64 * 4];  // 32 KB: [kchunk][n][4 x u32(bf16x2)]
    for (int p = threadIdx.x; p < (F_IN / 2) * F_OUT; p += 512) {
        int kp = p >> 6;
        int n = p & 63;
        int k = kp * 2;
        unsigned lo = f2bf_rne(W[k * F_OUT + n]);
        unsigned hi = f2bf_rne(W[(k + 1) * F_OUT + n]);
        Wf[((k >> 3) * 64 + n) * 4 + ((k & 7) >> 1)] = lo | (hi << 16);
    }
    __syncthreads();

    const int wave = threadIdx.x >> 6;
    const int lane = threadIdx.x & 63;
    const int q = lane >> 4;
    const int c = lane & 15;
    const int n0 = blockIdx.x * 128 + wave * 16;
    const int r = min(n0 + c, N - 1);
    const float* p0 = x + (size_t)r * F_IN + q * 8;

    f32x4 acc[4] = {};
#pragma unroll
    for (int s = 0; s < 8; s++) {
        float4 a0 = *(const float4*)(p0 + s * 32);
        float4 a1 = *(const float4*)(p0 + s * 32 + 4);
        short8 ah = pack_hi(a0, a1), al = pack_lo(a0, a1);
#pragma unroll
        for (int t = 0; t < 4; t++) {
            short8 bh = *(const short8*)&Wf[((s * 4 + q) * 64 + t * 16 + c) * 4];
            acc[t] = __builtin_amdgcn_mfma_f32_16x16x32_bf16(ah, bh, acc[t], 0, 0, 0);
            acc[t] = __builtin_amdgcn_mfma_f32_16x16x32_bf16(al, bh, acc[t], 0, 0, 0);
        }
    }

    // D layout: col = t*16 + c (feature), row = q*4 + rr (node). Pack col
    // pairs via shfl_xor(1), store bf16x2.
#pragma unroll
    for (int rr = 0; rr < 4; rr++) {
        int node = n0 + q * 4 + rr;
        float dv = rsqrtf((float)deg[min(node, N - 1)] + 1.0f);
#pragma unroll
        for (int t = 0; t < 4; t++) {
            float v = acc[t][rr] * dv;
            float o = __shfl_xor(v, 1, 64);
            if (node < N && !(lane & 1)) {
                unsigned pk = (unsigned)f2bf_rne(v) | ((unsigned)f2bf_rne(o) << 16);
                gu[(size_t)node * 32 + t * 8 + (c >> 1)] = pk;
            }
        }
    }
}

// ---------------------------------------------------------------------------
// K4: gather + fused epilogue. Wave = node; 4 quads, each loading csr[i],
// csr[i+4], csr[i+8], csr[i+12] with stride 16 -> quad q covers offsets
// == q (mod 4): FULL coverage (R8 bug: stride-16 loads covered only
// q mod 16, dropping 75% of edges). 16 edges in flight/wave.
// ---------------------------------------------------------------------------
__global__ __launch_bounds__(256) void gather_epilogue(const unsigned short* __restrict__ csr,
                                                       const int* __restrict__ rowOff,
                                                       const int* __restrict__ deg,
                                                       const unsigned* __restrict__ g32,
                                                       const float* __restrict__ bias,
                                                       float* __restrict__ out, int N) {
    int n = blockIdx.x * 4 + (threadIdx.x >> 6);
    if (n >= N) return;
    const int lane = threadIdx.x & 63;
    const int q = lane >> 4;
    const int h = lane & 15;
    const int start = rowOff[n], end = rowOff[n + 1];
    const uint2* g2 = (const uint2*)g32;

    float4 a0 = {0, 0, 0, 0}, a1 = {0, 0, 0, 0}, a2 = {0, 0, 0, 0}, a3 = {0, 0, 0, 0};
    int i = start + q;
    for (; i + 12 < end; i += 16) {
        int s0 = csr[i], s1 = csr[i + 4], s2 = csr[i + 8], s3 = csr[i + 12];
        uint2 u0 = g2[(size_t)s0 * 16 + h];
        uint2 u1 = g2[(size_t)s1 * 16 + h];
        uint2 u2 = g2[(size_t)s2 * 16 + h];
        uint2 u3 = g2[(size_t)s3 * 16 + h];
        a0.x += bf_lo(u0.x); a0.y += bf_hi(u0.x); a0.z += bf_lo(u0.y); a0.w += bf_hi(u0.y);
        a1.x += bf_lo(u1.x); a1.y += bf_hi(u1.x); a1.z += bf_lo(u1.y); a1.w += bf_hi(u1.y);
        a2.x += bf_lo(u2.x); a2.y += bf_hi(u2.x); a2.z += bf_lo(u2.y); a2.w += bf_hi(u2.y);
        a3.x += bf_lo(u3.x); a3.y += bf_hi(u3.x); a3.z += bf_lo(u3.y); a3.w += bf_hi(u3.y);
    }
    for (; i < end; i += 4) {
        int s0 = csr[i];
        uint2 u0 = g2[(size_t)s0 * 16 + h];
        a0.x += bf_lo(u0.x); a0.y += bf_hi(u0.x); a0.z += bf_lo(u0.y); a0.w += bf_hi(u0.y);
    }
    float4 acc;
    acc.x = (a0.x + a1.x) + (a2.x + a3.x);
    acc.y = (a0.y + a1.y) + (a2.y + a3.y);
    acc.z = (a0.z + a1.z) + (a2.z + a3.z);
    acc.w = (a0.w + a1.w) + (a2.w + a3.w);
    acc.x += __shfl_xor(acc.x, 16, 64);
    acc.y += __shfl_xor(acc.y, 16, 64);
    acc.z += __shfl_xor(acc.z, 16, 64);
    acc.w += __shfl_xor(acc.w, 16, 64);
    acc.x += __shfl_xor(acc.x, 32, 64);
    acc.y += __shfl_xor(acc.y, 32, 64);
    acc.z += __shfl_xor(acc.z, 32, 64);
    acc.w += __shfl_xor(acc.w, 32, 64);
    if (q == 0) {
        uint2 us = g2[(size_t)n * 16 + h];  // self loop
        float dv = rsqrtf((float)deg[n] + 1.0f);
        int c4 = h << 2;
        float4 bb = *(const float4*)&bias[c4];
        float4 r;
        r.x = fmaxf(fmaf(dv, acc.x + bf_lo(us.x), bb.x), 0.0f);
        r.y = fmaxf(fmaf(dv, acc.y + bf_hi(us.x), bb.y), 0.0f);
        r.z = fmaxf(fmaf(dv, acc.z + bf_lo(us.y), bb.z), 0.0f);
        r.w = fmaxf(fmaf(dv, acc.w + bf_hi(us.y), bb.w), 0.0f);
        *(float4*)&out[(size_t)n * F_OUT + c4] = r;
    }
}

extern "C" void kernel_launch(void* const* d_in, const int* in_sizes, int n_in,
                              void* d_out, int out_size, void* d_ws, size_t ws_size,
                              hipStream_t stream) {
    const float* x = (const float*)d_in[0];
    const int* adj = (const int*)d_in[1];
    const float* W = (const float*)d_in[2];
    const float* b = (const float*)d_in[3];
    float* out = (float*)d_out;

    const int N = in_sizes[0] / F_IN;  // 50000 (u32/u16 packing assumes N <= 65536)
    const int E = in_sizes[1] / 2;     // 800000
    const int nbins = (N + BINW - 1) >> BSH;             // 391 (<= NBINS_CAP)
    const int avg = (E + nbins - 1) / nbins;             // ~2047
    const int maxBin = ((avg + (avg >> 2)) + 63) & ~63;  // 2560, ~11 sd headroom

    // ws: deg(N) | cursor(512) | rowOff(N+1) | csr(E u16) | staging | g16
    char* ws = (char*)d_ws;
    size_t segDeg = (((size_t)N * 4) + 255) & ~(size_t)255;
    size_t segRow = (((size_t)(N + 1) * 4) + 255) & ~(size_t)255;
    size_t segCsr = (((size_t)E * 2) + 255) & ~(size_t)255;
    size_t segStg = (((size_t)nbins * maxBin * 4) + 255) & ~(size_t)255;
    int* deg = (int*)ws;
    int* cursor = (int*)(ws + segDeg);
    int* rowOff = (int*)(ws + segDeg + 2048);
    unsigned short* csr = (unsigned short*)(ws + segDeg + 2048 + segRow);
    unsigned* staging = (unsigned*)(ws + segDeg + 2048 + segRow + segCsr);
    unsigned* g16 = (unsigned*)(ws + segDeg + 2048 + segRow + segCsr + segStg);

    hipMemsetAsync(ws, 0, segDeg + 2048, stream);  // deg + cursor in one call

    bin_count<<<(E + BATCH - 1) / BATCH, 256, 0, stream>>>(adj, staging, cursor,
                                                           deg, E, nbins, maxBin);
    build_csr<<<nbins, 256, 0, stream>>>(staging, cursor, rowOff, csr, N, maxBin, nbins);
    gemm_mfma<<<(N + 127) / 128, 512, 0, stream>>>(x, W, deg, g16, N);
    gather_epilogue<<<(N + 3) / 4, 256, 0, stream>>>(csr, rowOff, deg, g16, b, out, N);
}

// Round 10
// 171.393 us; speedup vs baseline: 2.8811x; 1.0497x over previous
//
#include <hip/hip_runtime.h>

#define F_IN 256
#define F_OUT 64
#define BSH 7             // bin width 128 nodes
#define BINW 128
#define NBINS_CAP 512     // LDS histogram capacity in bin_count (N <= 65536)
#define BATCH 1024        // edges per block in bin_count (4 per thread)
#define CSTRIDE 16        // cursor padded to one 64B line per bin

typedef __attribute__((ext_vector_type(8))) short short8;
typedef __attribute__((ext_vector_type(4))) float f32x4;

// ---------------------------------------------------------------------------
// bf16 helpers. hi = truncated bf16, lo = RNE bf16 of exact residual.
// ---------------------------------------------------------------------------
__device__ inline unsigned short f2bf_rne(float f) {
    unsigned u = __float_as_uint(f);
    return (unsigned short)((u + 0x7fffu + ((u >> 16) & 1u)) >> 16);
}
__device__ inline float trunc_res(float f) {
    return f - __uint_as_float(__float_as_uint(f) & 0xFFFF0000u);
}
__device__ inline float bf_lo(unsigned u) { return __uint_as_float(u << 16); }
__device__ inline float bf_hi(unsigned u) { return __uint_as_float(u & 0xFFFF0000u); }
__device__ inline short8 pack_hi(float4 a, float4 b) {
    union { unsigned u[4]; short8 s; } r;
    r.u[0] = (__float_as_uint(a.x) >> 16) | (__float_as_uint(a.y) & 0xFFFF0000u);
    r.u[1] = (__float_as_uint(a.z) >> 16) | (__float_as_uint(a.w) & 0xFFFF0000u);
    r.u[2] = (__float_as_uint(b.x) >> 16) | (__float_as_uint(b.y) & 0xFFFF0000u);
    r.u[3] = (__float_as_uint(b.z) >> 16) | (__float_as_uint(b.w) & 0xFFFF0000u);
    return r.s;
}
__device__ inline short8 pack_lo(float4 a, float4 b) {
    union { unsigned u[4]; short8 s; } r;
    r.u[0] = f2bf_rne(trunc_res(a.x)) | ((unsigned)f2bf_rne(trunc_res(a.y)) << 16);
    r.u[1] = f2bf_rne(trunc_res(a.z)) | ((unsigned)f2bf_rne(trunc_res(a.w)) << 16);
    r.u[2] = f2bf_rne(trunc_res(b.x)) | ((unsigned)f2bf_rne(trunc_res(b.y)) << 16);
    r.u[3] = f2bf_rne(trunc_res(b.z)) | ((unsigned)f2bf_rne(trunc_res(b.w)) << 16);
    return r.s;
}

// ---------------------------------------------------------------------------
// K1: bin edges by dst>>BSH into per-bin staging (packed u32: src | dstLow<<16,
// valid for N <= 65536). R9 lesson: the per-block base round (391 atomic-with-
// return on a 24-line cursor array) serialized at the L2 banks -> 46us.
// Fix: cursor padded to one 64B line per bin (parallel across banks), deg
// atomics removed (dinv now computed in build_csr from its LDS histogram),
// 782 blocks (3/CU) so atomic-latency phases overlap.
// ---------------------------------------------------------------------------
__global__ __launch_bounds__(256) void bin_count(const int* __restrict__ adj,
                                                 unsigned* __restrict__ staging,
                                                 int* __restrict__ cursor,
                                                 int E, int nbins, int maxBin) {
    __shared__ int cnt[NBINS_CAP];
    __shared__ int base[NBINS_CAP];
    const int tid = threadIdx.x;
    for (int i = tid; i < NBINS_CAP; i += 256) cnt[i] = 0;
    __syncthreads();

    const int e0 = blockIdx.x * BATCH;
    const int e1 = min(e0 + BATCH, E);
    const int e = e0 + tid * 4;
    union { int4 v; int a[4]; } S, D;
    int sl[4];
    int nv = 0;
    if (e < e1) {
        if (e + 4 <= e1 && ((E & 3) == 0)) {
            S.v = *(const int4*)&adj[e];
            D.v = *(const int4*)&adj[E + e];
            nv = 4;
        } else {
            for (int k = 0; k < 4 && e + k < e1; k++) {
                S.a[k] = adj[e + k];
                D.a[k] = adj[E + e + k];
                nv++;
            }
        }
    }
#pragma unroll
    for (int j = 0; j < 4; j++) {
        if (j < nv) sl[j] = atomicAdd(&cnt[D.a[j] >> BSH], 1);
    }
    __syncthreads();
    for (int i = tid; i < nbins; i += 256)
        base[i] = atomicAdd(&cursor[i * CSTRIDE], cnt[i]);
    __syncthreads();
#pragma unroll
    for (int j = 0; j < 4; j++) {
        if (j < nv) {
            int b = D.a[j] >> BSH;
            int pos = base[b] + sl[j];
            if (pos < maxBin)
                staging[(size_t)b * maxBin + pos] =
                    (unsigned)S.a[j] | ((unsigned)(D.a[j] & (BINW - 1)) << 16);
        }
    }
}

// ---------------------------------------------------------------------------
// K2: fused scan+scatter, one block per 128-node bin (391-way parallel).
// Wave 0 reduces prior-bin counts for the global base; LDS histogram of
// staged dstLows; 2-wave exclusive scan; write rowOff AND dinv=rsqrt(deg+1);
// scatter srcs into csr (ushort) via LDS cursors (one ~4KB window per block).
// ---------------------------------------------------------------------------
__global__ __launch_bounds__(256) void build_csr(const unsigned* __restrict__ staging,
                                                 const int* __restrict__ cursor,
                                                 int* __restrict__ rowOff,
                                                 float* __restrict__ dinv,
                                                 unsigned short* __restrict__ csr,
                                                 int N, int maxBin, int nbins) {
    __shared__ int degL[BINW];
    __shared__ int cur[BINW];
    __shared__ int wsum[2];
    __shared__ int baseSh;
    const int b = blockIdx.x;
    const int tid = threadIdx.x;
    const int nb0 = b << BSH;
    const int segCnt = min(cursor[b * CSTRIDE], maxBin);
    const unsigned* seg = staging + (size_t)b * maxBin;

    if (tid < 64) {  // base = staged edges in bins before this one
        int v = 0;
        for (int j = tid; j < b; j += 64) v += min(cursor[j * CSTRIDE], maxBin);
        for (int d = 1; d < 64; d <<= 1) v += __shfl_xor(v, d, 64);
        if (tid == 0) baseSh = v;
    }
    if (tid < BINW) degL[tid] = 0;
    __syncthreads();
    const int base = baseSh;

    for (int i = tid; i < segCnt; i += 256) atomicAdd(&degL[seg[i] >> 16], 1);
    __syncthreads();

    int incl = 0, v = 0;
    if (tid < BINW) {  // 2-wave exclusive scan of degL[128]
        const int lane = tid & 63;
        v = degL[tid];
        incl = v;
        for (int d = 1; d < 64; d <<= 1) {
            int t = __shfl_up(incl, d, 64);
            if (lane >= d) incl += t;
        }
        if (lane == 63) wsum[tid >> 6] = incl;
    }
    __syncthreads();
    if (tid < BINW) {
        int ex = incl - v + ((tid >= 64) ? wsum[0] : 0);
        cur[tid] = ex;
        int node = nb0 + tid;
        if (node < N) {
            rowOff[node] = base + ex;
            dinv[node] = rsqrtf((float)v + 1.0f);
        }
    }
    if (b == nbins - 1 && tid == 0) rowOff[N] = base + segCnt;
    __syncthreads();

    for (int i = tid; i < segCnt; i += 256) {
        unsigned e = seg[i];
        int pos = atomicAdd(&cur[e >> 16], 1);
        csr[base + pos] = (unsigned short)(e & 0xFFFFu);
    }
}

// ---------------------------------------------------------------------------
// K3: g(bf16) = dinv[n] * (x @ W) via bf16 MFMA, x = hi+lo split (near-fp32).
// 512-thread blocks, 16 nodes/wave, W staged per block into B-fragment-major
// LDS (u32-packed bf16 pairs, 32 KB).
// ---------------------------------------------------------------------------
__global__ __launch_bounds__(512, 4) void gemm_mfma(const float* __restrict__ x,
                                                    const float* __restrict__ W,
                                                    const float* __restrict__ dinv,
                                                    unsigned* __restrict__ gu, int N) {
    __shared__ unsigned Wf[32 * 64 * 4];  // 32 KB: [kchunk][n][4 x u32(bf16x2)]
    for (int p = threadIdx.x; p < (F_IN / 2) * F_OUT; p += 512) {
        int kp = p >> 6;
        int n = p & 63;
        int k = kp * 2;
        unsigned lo = f2bf_rne(W[k * F_OUT + n]);
        unsigned hi = f2bf_rne(W[(k + 1) * F_OUT + n]);
        Wf[((k >> 3) * 64 + n) * 4 + ((k & 7) >> 1)] = lo | (hi << 16);
    }
    __syncthreads();

    const int wave = threadIdx.x >> 6;
    const int lane = threadIdx.x & 63;
    const int q = lane >> 4;
    const int c = lane & 15;
    const int n0 = blockIdx.x * 128 + wave * 16;
    const int r = min(n0 + c, N - 1);
    const float* p0 = x + (size_t)r * F_IN + q * 8;

    f32x4 acc[4] = {};
#pragma unroll
    for (int s = 0; s < 8; s++) {
        float4 a0 = *(const float4*)(p0 + s * 32);
        float4 a1 = *(const float4*)(p0 + s * 32 + 4);
        short8 ah = pack_hi(a0, a1), al = pack_lo(a0, a1);
#pragma unroll
        for (int t = 0; t < 4; t++) {
            short8 bh = *(const short8*)&Wf[((s * 4 + q) * 64 + t * 16 + c) * 4];
            acc[t] = __builtin_amdgcn_mfma_f32_16x16x32_bf16(ah, bh, acc[t], 0, 0, 0);
            acc[t] = __builtin_amdgcn_mfma_f32_16x16x32_bf16(al, bh, acc[t], 0, 0, 0);
        }
    }

    // D layout: col = t*16 + c (feature), row = q*4 + rr (node). Pack col
    // pairs via shfl_xor(1), store bf16x2.
#pragma unroll
    for (int rr = 0; rr < 4; rr++) {
        int node = n0 + q * 4 + rr;
        float dv = dinv[min(node, N - 1)];
#pragma unroll
        for (int t = 0; t < 4; t++) {
            float v = acc[t][rr] * dv;
            float o = __shfl_xor(v, 1, 64);
            if (node < N && !(lane & 1)) {
                unsigned pk = (unsigned)f2bf_rne(v) | ((unsigned)f2bf_rne(o) << 16);
                gu[(size_t)node * 32 + t * 8 + (c >> 1)] = pk;
            }
        }
    }
}

// ---------------------------------------------------------------------------
// K4: gather + fused epilogue. Wave = node; 4 quads, each loading csr[i],
// csr[i+4], csr[i+8], csr[i+12] with stride 16 -> quad q covers offsets
// == q (mod 4): full coverage, 16 edges in flight/wave.
// ---------------------------------------------------------------------------
__global__ __launch_bounds__(256) void gather_epilogue(const unsigned short* __restrict__ csr,
                                                       const int* __restrict__ rowOff,
                                                       const float* __restrict__ dinv,
                                                       const unsigned* __restrict__ g32,
                                                       const float* __restrict__ bias,
                                                       float* __restrict__ out, int N) {
    int n = blockIdx.x * 4 + (threadIdx.x >> 6);
    if (n >= N) return;
    const int lane = threadIdx.x & 63;
    const int q = lane >> 4;
    const int h = lane & 15;
    const int start = rowOff[n], end = rowOff[n + 1];
    const uint2* g2 = (const uint2*)g32;

    float4 a0 = {0, 0, 0, 0}, a1 = {0, 0, 0, 0}, a2 = {0, 0, 0, 0}, a3 = {0, 0, 0, 0};
    int i = start + q;
    for (; i + 12 < end; i += 16) {
        int s0 = csr[i], s1 = csr[i + 4], s2 = csr[i + 8], s3 = csr[i + 12];
        uint2 u0 = g2[(size_t)s0 * 16 + h];
        uint2 u1 = g2[(size_t)s1 * 16 + h];
        uint2 u2 = g2[(size_t)s2 * 16 + h];
        uint2 u3 = g2[(size_t)s3 * 16 + h];
        a0.x += bf_lo(u0.x); a0.y += bf_hi(u0.x); a0.z += bf_lo(u0.y); a0.w += bf_hi(u0.y);
        a1.x += bf_lo(u1.x); a1.y += bf_hi(u1.x); a1.z += bf_lo(u1.y); a1.w += bf_hi(u1.y);
        a2.x += bf_lo(u2.x); a2.y += bf_hi(u2.x); a2.z += bf_lo(u2.y); a2.w += bf_hi(u2.y);
        a3.x += bf_lo(u3.x); a3.y += bf_hi(u3.x); a3.z += bf_lo(u3.y); a3.w += bf_hi(u3.y);
    }
    for (; i < end; i += 4) {
        int s0 = csr[i];
        uint2 u0 = g2[(size_t)s0 * 16 + h];
        a0.x += bf_lo(u0.x); a0.y += bf_hi(u0.x); a0.z += bf_lo(u0.y); a0.w += bf_hi(u0.y);
    }
    float4 acc;
    acc.x = (a0.x + a1.x) + (a2.x + a3.x);
    acc.y = (a0.y + a1.y) + (a2.y + a3.y);
    acc.z = (a0.z + a1.z) + (a2.z + a3.z);
    acc.w = (a0.w + a1.w) + (a2.w + a3.w);
    acc.x += __shfl_xor(acc.x, 16, 64);
    acc.y += __shfl_xor(acc.y, 16, 64);
    acc.z += __shfl_xor(acc.z, 16, 64);
    acc.w += __shfl_xor(acc.w, 16, 64);
    acc.x += __shfl_xor(acc.x, 32, 64);
    acc.y += __shfl_xor(acc.y, 32, 64);
    acc.z += __shfl_xor(acc.z, 32, 64);
    acc.w += __shfl_xor(acc.w, 32, 64);
    if (q == 0) {
        uint2 us = g2[(size_t)n * 16 + h];  // self loop
        float dv = dinv[n];
        int c4 = h << 2;
        float4 bb = *(const float4*)&bias[c4];
        float4 r;
        r.x = fmaxf(fmaf(dv, acc.x + bf_lo(us.x), bb.x), 0.0f);
        r.y = fmaxf(fmaf(dv, acc.y + bf_hi(us.x), bb.y), 0.0f);
        r.z = fmaxf(fmaf(dv, acc.z + bf_lo(us.y), bb.z), 0.0f);
        r.w = fmaxf(fmaf(dv, acc.w + bf_hi(us.y), bb.w), 0.0f);
        *(float4*)&out[(size_t)n * F_OUT + c4] = r;
    }
}

extern "C" void kernel_launch(void* const* d_in, const int* in_sizes, int n_in,
                              void* d_out, int out_size, void* d_ws, size_t ws_size,
                              hipStream_t stream) {
    const float* x = (const float*)d_in[0];
    const int* adj = (const int*)d_in[1];
    const float* W = (const float*)d_in[2];
    const float* b = (const float*)d_in[3];
    float* out = (float*)d_out;

    const int N = in_sizes[0] / F_IN;  // 50000 (u32/u16 packing assumes N <= 65536)
    const int E = in_sizes[1] / 2;     // 800000
    const int nbins = (N + BINW - 1) >> BSH;             // 391 (<= NBINS_CAP)
    const int avg = (E + nbins - 1) / nbins;             // ~2047
    const int maxBin = ((avg + (avg >> 2)) + 63) & ~63;  // 2560, ~11 sd headroom

    // ws: dinv(N) | cursor(nbins*64B, padded) | rowOff(N+1) | csr(E u16) |
    //     staging(nbins*maxBin u32) | g16(N*32 u32)
    char* ws = (char*)d_ws;
    size_t segDinv = (((size_t)N * 4) + 255) & ~(size_t)255;
    size_t segCur = (((size_t)nbins * CSTRIDE * 4) + 255) & ~(size_t)255;
    size_t segRow = (((size_t)(N + 1) * 4) + 255) & ~(size_t)255;
    size_t segCsr = (((size_t)E * 2) + 255) & ~(size_t)255;
    size_t segStg = (((size_t)nbins * maxBin * 4) + 255) & ~(size_t)255;
    float* dinv = (float*)ws;
    int* cursor = (int*)(ws + segDinv);
    int* rowOff = (int*)(ws + segDinv + segCur);
    unsigned short* csr = (unsigned short*)(ws + segDinv + segCur + segRow);
    unsigned* staging = (unsigned*)(ws + segDinv + segCur + segRow + segCsr);
    unsigned* g16 = (unsigned*)(ws + segDinv + segCur + segRow + segCsr + segStg);

    hipMemsetAsync(cursor, 0, segCur, stream);

    bin_count<<<(E + BATCH - 1) / BATCH, 256, 0, stream>>>(adj, staging, cursor,
                                                           E, nbins, maxBin);
    build_csr<<<nbins, 256, 0, stream>>>(staging, cursor, rowOff, dinv, csr,
                                         N, maxBin, nbins);
    gemm_mfma<<<(N + 127) / 128, 512, 0, stream>>>(x, W, dinv, g16, N);
    gather_epilogue<<<(N + 3) / 4, 256, 0, stream>>>(csr, rowOff, dinv, g16, b, out, N);
}

// Round 11
// 169.819 us; speedup vs baseline: 2.9078x; 1.0093x over previous
//
#include <hip/hip_runtime.h>

#define F_IN 256
#define F_OUT 64
#define BSH 7             // bin width 128 nodes
#define BINW 128
#define NBINS_CAP 512     // LDS histogram capacity in bin_count (N <= 65536)
#define BATCH 1024        // edges per block in bin_count (4 per thread)
#define CSTRIDE 16        // cursor padded to one 64B line per bin

typedef __attribute__((ext_vector_type(8))) short short8;
typedef __attribute__((ext_vector_type(4))) float f32x4;

// ---------------------------------------------------------------------------
// bf16 helpers (RNE).
// ---------------------------------------------------------------------------
__device__ inline unsigned short f2bf_rne(float f) {
    unsigned u = __float_as_uint(f);
    return (unsigned short)((u + 0x7fffu + ((u >> 16) & 1u)) >> 16);
}
__device__ inline float bf_lo(unsigned u) { return __uint_as_float(u << 16); }
__device__ inline float bf_hi(unsigned u) { return __uint_as_float(u & 0xFFFF0000u); }
// Pack 8 floats -> 8 RNE bf16 (A-fragment order: [k0,k1][k2,k3][k4,k5][k6,k7]).
__device__ inline short8 pack_rne(float4 a, float4 b) {
    union { unsigned u[4]; short8 s; } r;
    r.u[0] = f2bf_rne(a.x) | ((unsigned)f2bf_rne(a.y) << 16);
    r.u[1] = f2bf_rne(a.z) | ((unsigned)f2bf_rne(a.w) << 16);
    r.u[2] = f2bf_rne(b.x) | ((unsigned)f2bf_rne(b.y) << 16);
    r.u[3] = f2bf_rne(b.z) | ((unsigned)f2bf_rne(b.w) << 16);
    return r.s;
}

// ---------------------------------------------------------------------------
// K1: bin edges by dst>>BSH into per-bin staging (packed u32: src | dstLow<<16,
// valid for N <= 65536). Cursor padded to one 64B line per bin (R9 lesson:
// unpadded cursor serialized the atomic-with-return rounds at L2 -> 46us).
// ---------------------------------------------------------------------------
__global__ __launch_bounds__(256) void bin_count(const int* __restrict__ adj,
                                                 unsigned* __restrict__ staging,
                                                 int* __restrict__ cursor,
                                                 int E, int nbins, int maxBin) {
    __shared__ int cnt[NBINS_CAP];
    __shared__ int base[NBINS_CAP];
    const int tid = threadIdx.x;
    for (int i = tid; i < NBINS_CAP; i += 256) cnt[i] = 0;
    __syncthreads();

    const int e0 = blockIdx.x * BATCH;
    const int e1 = min(e0 + BATCH, E);
    const int e = e0 + tid * 4;
    union { int4 v; int a[4]; } S, D;
    int sl[4];
    int nv = 0;
    if (e < e1) {
        if (e + 4 <= e1 && ((E & 3) == 0)) {
            S.v = *(const int4*)&adj[e];
            D.v = *(const int4*)&adj[E + e];
            nv = 4;
        } else {
            for (int k = 0; k < 4 && e + k < e1; k++) {
                S.a[k] = adj[e + k];
                D.a[k] = adj[E + e + k];
                nv++;
            }
        }
    }
#pragma unroll
    for (int j = 0; j < 4; j++) {
        if (j < nv) sl[j] = atomicAdd(&cnt[D.a[j] >> BSH], 1);
    }
    __syncthreads();
    for (int i = tid; i < nbins; i += 256)
        base[i] = atomicAdd(&cursor[i * CSTRIDE], cnt[i]);
    __syncthreads();
#pragma unroll
    for (int j = 0; j < 4; j++) {
        if (j < nv) {
            int b = D.a[j] >> BSH;
            int pos = base[b] + sl[j];
            if (pos < maxBin)
                staging[(size_t)b * maxBin + pos] =
                    (unsigned)S.a[j] | ((unsigned)(D.a[j] & (BINW - 1)) << 16);
        }
    }
}

// ---------------------------------------------------------------------------
// K2: fused scan+scatter, one block per 128-node bin (391-way parallel).
// Wave 0 reduces prior-bin counts for the global base; LDS histogram of
// staged dstLows; 2-wave exclusive scan; write rowOff AND dinv=rsqrt(deg+1);
// scatter srcs into csr (ushort) via LDS cursors (one ~4KB window per block).
// ---------------------------------------------------------------------------
__global__ __launch_bounds__(256) void build_csr(const unsigned* __restrict__ staging,
                                                 const int* __restrict__ cursor,
                                                 int* __restrict__ rowOff,
                                                 float* __restrict__ dinv,
                                                 unsigned short* __restrict__ csr,
                                                 int N, int maxBin, int nbins) {
    __shared__ int degL[BINW];
    __shared__ int cur[BINW];
    __shared__ int wsum[2];
    __shared__ int baseSh;
    const int b = blockIdx.x;
    const int tid = threadIdx.x;
    const int nb0 = b << BSH;
    const int segCnt = min(cursor[b * CSTRIDE], maxBin);
    const unsigned* seg = staging + (size_t)b * maxBin;

    if (tid < 64) {  // base = staged edges in bins before this one
        int v = 0;
        for (int j = tid; j < b; j += 64) v += min(cursor[j * CSTRIDE], maxBin);
        for (int d = 1; d < 64; d <<= 1) v += __shfl_xor(v, d, 64);
        if (tid == 0) baseSh = v;
    }
    if (tid < BINW) degL[tid] = 0;
    __syncthreads();
    const int base = baseSh;

    for (int i = tid; i < segCnt; i += 256) atomicAdd(&degL[seg[i] >> 16], 1);
    __syncthreads();

    int incl = 0, v = 0;
    if (tid < BINW) {  // 2-wave exclusive scan of degL[128]
        const int lane = tid & 63;
        v = degL[tid];
        incl = v;
        for (int d = 1; d < 64; d <<= 1) {
            int t = __shfl_up(incl, d, 64);
            if (lane >= d) incl += t;
        }
        if (lane == 63) wsum[tid >> 6] = incl;
    }
    __syncthreads();
    if (tid < BINW) {
        int ex = incl - v + ((tid >= 64) ? wsum[0] : 0);
        cur[tid] = ex;
        int node = nb0 + tid;
        if (node < N) {
            rowOff[node] = base + ex;
            dinv[node] = rsqrtf((float)v + 1.0f);
        }
    }
    if (b == nbins - 1 && tid == 0) rowOff[N] = base + segCnt;
    __syncthreads();

    for (int i = tid; i < segCnt; i += 256) {
        unsigned e = seg[i];
        int pos = atomicAdd(&cur[e >> 16], 1);
        csr[base + pos] = (unsigned short)(e & 0xFFFFu);
    }
}

// ---------------------------------------------------------------------------
// K3: g(bf16) = dinv[n] * (x @ W) via bf16 MFMA, x as single RNE bf16.
// R10 was pack-VALU-bound (hi+lo split: ~100 VALU cyc/k-chunk vs 16 MFMA);
// W/g rounding already dominates the error budget (absmax 7.8e-3 vs 26.6e-3
// threshold), so the lo term buys nothing we need. Halves MFMAs, cuts pack
// VALU ~3x. 512-thread blocks, 16 nodes/wave, W in B-fragment-major LDS.
// ---------------------------------------------------------------------------
__global__ __launch_bounds__(512, 4) void gemm_mfma(const float* __restrict__ x,
                                                    const float* __restrict__ W,
                                                    const float* __restrict__ dinv,
                                                    unsigned* __restrict__ gu, int N) {
    __shared__ unsigned Wf[32 * 64 * 4];  // 32 KB: [kchunk][n][4 x u32(bf16x2)]
    for (int p = threadIdx.x; p < (F_IN / 2) * F_OUT; p += 512) {
        int kp = p >> 6;
        int n = p & 63;
        int k = kp * 2;
        unsigned lo = f2bf_rne(W[k * F_OUT + n]);
        unsigned hi = f2bf_rne(W[(k + 1) * F_OUT + n]);
        Wf[((k >> 3) * 64 + n) * 4 + ((k & 7) >> 1)] = lo | (hi << 16);
    }
    __syncthreads();

    const int wave = threadIdx.x >> 6;
    const int lane = threadIdx.x & 63;
    const int q = lane >> 4;
    const int c = lane & 15;
    const int n0 = blockIdx.x * 128 + wave * 16;
    const int r = min(n0 + c, N - 1);
    const float* p0 = x + (size_t)r * F_IN + q * 8;

    f32x4 acc[4] = {};
#pragma unroll
    for (int s = 0; s < 8; s++) {
        float4 a0 = *(const float4*)(p0 + s * 32);
        float4 a1 = *(const float4*)(p0 + s * 32 + 4);
        short8 ah = pack_rne(a0, a1);
#pragma unroll
        for (int t = 0; t < 4; t++) {
            short8 bh = *(const short8*)&Wf[((s * 4 + q) * 64 + t * 16 + c) * 4];
            acc[t] = __builtin_amdgcn_mfma_f32_16x16x32_bf16(ah, bh, acc[t], 0, 0, 0);
        }
    }

    // D layout: col = t*16 + c (feature), row = q*4 + rr (node). Pack col
    // pairs via shfl_xor(1), store bf16x2.
#pragma unroll
    for (int rr = 0; rr < 4; rr++) {
        int node = n0 + q * 4 + rr;
        float dv = dinv[min(node, N - 1)];
#pragma unroll
        for (int t = 0; t < 4; t++) {
            float v = acc[t][rr] * dv;
            float o = __shfl_xor(v, 1, 64);
            if (node < N && !(lane & 1)) {
                unsigned pk = (unsigned)f2bf_rne(v) | ((unsigned)f2bf_rne(o) << 16);
                gu[(size_t)node * 32 + t * 8 + (c >> 1)] = pk;
            }
        }
    }
}

// ---------------------------------------------------------------------------
// K4: gather + fused epilogue. Wave = node; 8 groups of 8 lanes, each lane
// loads uint4 (16B, cols 8h..8h+7) -> one 128B request per group per edge.
// 2-deep unroll: at avg deg 16 each group runs exactly one full iteration
// (2 loads in flight, 16/wave). Cross-group reduce via shfl_xor 8/16/32.
// ---------------------------------------------------------------------------
__global__ __launch_bounds__(256) void gather_epilogue(const unsigned short* __restrict__ csr,
                                                       const int* __restrict__ rowOff,
                                                       const float* __restrict__ dinv,
                                                       const unsigned* __restrict__ g32,
                                                       const float* __restrict__ bias,
                                                       float* __restrict__ out, int N) {
    int n = blockIdx.x * 4 + (threadIdx.x >> 6);
    if (n >= N) return;
    const int lane = threadIdx.x & 63;
    const int grp = lane >> 3;
    const int h = lane & 7;
    const int start = rowOff[n], end = rowOff[n + 1];
    const uint4* g4 = (const uint4*)g32;

    float a0[8] = {}, a1[8] = {};
    int i = start + grp;
    for (; i + 8 < end; i += 16) {
        int s0 = csr[i], s1 = csr[i + 8];
        uint4 u0 = g4[(size_t)s0 * 8 + h];
        uint4 u1 = g4[(size_t)s1 * 8 + h];
        a0[0] += bf_lo(u0.x); a0[1] += bf_hi(u0.x);
        a0[2] += bf_lo(u0.y); a0[3] += bf_hi(u0.y);
        a0[4] += bf_lo(u0.z); a0[5] += bf_hi(u0.z);
        a0[6] += bf_lo(u0.w); a0[7] += bf_hi(u0.w);
        a1[0] += bf_lo(u1.x); a1[1] += bf_hi(u1.x);
        a1[2] += bf_lo(u1.y); a1[3] += bf_hi(u1.y);
        a1[4] += bf_lo(u1.z); a1[5] += bf_hi(u1.z);
        a1[6] += bf_lo(u1.w); a1[7] += bf_hi(u1.w);
    }
    if (i < end) {
        int s0 = csr[i];
        uint4 u0 = g4[(size_t)s0 * 8 + h];
        a0[0] += bf_lo(u0.x); a0[1] += bf_hi(u0.x);
        a0[2] += bf_lo(u0.y); a0[3] += bf_hi(u0.y);
        a0[4] += bf_lo(u0.z); a0[5] += bf_hi(u0.z);
        a0[6] += bf_lo(u0.w); a0[7] += bf_hi(u0.w);
    }
    float acc[8];
#pragma unroll
    for (int k = 0; k < 8; k++) acc[k] = a0[k] + a1[k];
#pragma unroll
    for (int m = 8; m < 64; m <<= 1) {
#pragma unroll
        for (int k = 0; k < 8; k++) acc[k] += __shfl_xor(acc[k], m, 64);
    }
    if (grp == 0) {
        uint4 us = g4[(size_t)n * 8 + h];  // self loop
        float dv = dinv[n];
        float s0 = bf_lo(us.x), s1 = bf_hi(us.x), s2 = bf_lo(us.y), s3 = bf_hi(us.y);
        float s4 = bf_lo(us.z), s5 = bf_hi(us.z), s6 = bf_lo(us.w), s7 = bf_hi(us.w);
        float4 b0 = *(const float4*)&bias[h * 8];
        float4 b1 = *(const float4*)&bias[h * 8 + 4];
        float4 r0, r1;
        r0.x = fmaxf(fmaf(dv, acc[0] + s0, b0.x), 0.0f);
        r0.y = fmaxf(fmaf(dv, acc[1] + s1, b0.y), 0.0f);
        r0.z = fmaxf(fmaf(dv, acc[2] + s2, b0.z), 0.0f);
        r0.w = fmaxf(fmaf(dv, acc[3] + s3, b0.w), 0.0f);
        r1.x = fmaxf(fmaf(dv, acc[4] + s4, b1.x), 0.0f);
        r1.y = fmaxf(fmaf(dv, acc[5] + s5, b1.y), 0.0f);
        r1.z = fmaxf(fmaf(dv, acc[6] + s6, b1.z), 0.0f);
        r1.w = fmaxf(fmaf(dv, acc[7] + s7, b1.w), 0.0f);
        *(float4*)&out[(size_t)n * F_OUT + h * 8] = r0;
        *(float4*)&out[(size_t)n * F_OUT + h * 8 + 4] = r1;
    }
}

extern "C" void kernel_launch(void* const* d_in, const int* in_sizes, int n_in,
                              void* d_out, int out_size, void* d_ws, size_t ws_size,
                              hipStream_t stream) {
    const float* x = (const float*)d_in[0];
    const int* adj = (const int*)d_in[1];
    const float* W = (const float*)d_in[2];
    const float* b = (const float*)d_in[3];
    float* out = (float*)d_out;

    const int N = in_sizes[0] / F_IN;  // 50000 (u32/u16 packing assumes N <= 65536)
    const int E = in_sizes[1] / 2;     // 800000
    const int nbins = (N + BINW - 1) >> BSH;             // 391 (<= NBINS_CAP)
    const int avg = (E + nbins - 1) / nbins;             // ~2047
    const int maxBin = ((avg + (avg >> 2)) + 63) & ~63;  // 2560, ~11 sd headroom

    // ws: dinv(N) | cursor(nbins*64B, padded) | rowOff(N+1) | csr(E u16) |
    //     staging(nbins*maxBin u32) | g16(N*32 u32)
    char* ws = (char*)d_ws;
    size_t segDinv = (((size_t)N * 4) + 255) & ~(size_t)255;
    size_t segCur = (((size_t)nbins * CSTRIDE * 4) + 255) & ~(size_t)255;
    size_t segRow = (((size_t)(N + 1) * 4) + 255) & ~(size_t)255;
    size_t segCsr = (((size_t)E * 2) + 255) & ~(size_t)255;
    size_t segStg = (((size_t)nbins * maxBin * 4) + 255) & ~(size_t)255;
    float* dinv = (float*)ws;
    int* cursor = (int*)(ws + segDinv);
    int* rowOff = (int*)(ws + segDinv + segCur);
    unsigned short* csr = (unsigned short*)(ws + segDinv + segCur + segRow);
    unsigned* staging = (unsigned*)(ws + segDinv + segCur + segRow + segCsr);
    unsigned* g16 = (unsigned*)(ws + segDinv + segCur + segRow + segCsr + segStg);

    hipMemsetAsync(cursor, 0, segCur, stream);

    bin_count<<<(E + BATCH - 1) / BATCH, 256, 0, stream>>>(adj, staging, cursor,
                                                           E, nbins, maxBin);
    build_csr<<<nbins, 256, 0, stream>>>(staging, cursor, rowOff, dinv, csr,
                                         N, maxBin, nbins);
    gemm_mfma<<<(N + 127) / 128, 512, 0, stream>>>(x, W, dinv, g16, N);
    gather_epilogue<<<(N + 3) / 4, 256, 0, stream>>>(csr, rowOff, dinv, g16, b, out, N);
}